// Round 6
// baseline (406.018 us; speedup 1.0000x reference)
//
#include <hip/hip_runtime.h>

#define N_RAYS 16384
#define MAX_STEPS 512
#define GRID_R 128
#define N_CELLS (GRID_R * GRID_R * GRID_R) /* 2097152 */
#define NS (N_RAYS * MAX_STEPS)            /* 8388608 samples */

typedef float vfloat4 __attribute__((ext_vector_type(4)));
typedef float vfloat2 __attribute__((ext_vector_type(2)));

// ws layout (bytes):
//   [0)       flag (fallback only)
//   [1024)    counts (16384 ints)
//   [131072)  bit grid (N_CELLS/8 = 262144 B)
#define WS_COUNTS_OFF 1024
#define WS_BITS_OFF 131072
#define WS_NEEDED (WS_BITS_OFF + N_CELLS / 8)

// ---------------------------------------------------------------------------
// pack_occ: self-detects occ dtype from the global first 1024 words (uniform
// across all blocks), then compresses its 256-cell slice to 1 bit/cell.
// mode 0 = int32 (0/1), mode 1 = float32 (0.0/1.0), mode 2 = uint8.
// ---------------------------------------------------------------------------
__global__ __launch_bounds__(256)
void pack_occ(const void* __restrict__ occ, unsigned long long* __restrict__ bits) {
    const int* pi = (const int*)occ;
    const float* pf = (const float*)occ;
    bool oki = true, okf = true;
#pragma unroll
    for (int k = 0; k < 4; ++k) {
        const int w = threadIdx.x * 4 + k;
        const int v = pi[w];
        oki = oki && (v == 0 || v == 1);
        const float f = pf[w];
        okf = okf && (f == 0.0f || f == 1.0f);
    }
    oki = __all(oki); okf = __all(okf);
    __shared__ int s_oki[4], s_okf[4];
    if ((threadIdx.x & 63) == 0) { s_oki[threadIdx.x >> 6] = oki; s_okf[threadIdx.x >> 6] = okf; }
    __syncthreads();
    const bool all_i = s_oki[0] && s_oki[1] && s_oki[2] && s_oki[3];
    const bool all_f = s_okf[0] && s_okf[1] && s_okf[2] && s_okf[3];
    const int mode = all_i ? 0 : (all_f ? 1 : 2);

    const int idx = blockIdx.x * 256 + threadIdx.x;
    bool v;
    if (mode == 0)      v = pi[idx] != 0;
    else if (mode == 1) v = pf[idx] != 0.0f;
    else                v = ((const unsigned char*)occ)[idx] != 0;
    const unsigned long long b = __ballot(v);
    if ((threadIdx.x & 63) == 0) bits[idx >> 6] = b;
}

// ---------------------------------------------------------------------------
// sample_kernel: one block per ray (512 threads), one thread per step.
// _rn arithmetic throughout (numpy ref = no FMA contraction).
//
// Store strategy (round-6): each wave's __ballot already holds the wave's
// full 64-sample validity mask in-register, so every wave writes ONLY its own
// 64-sample window of each output region -> no LDS mask, no __syncthreads in
// front of the store stream. 160 float4 per wave in 3 predicated passes.
// LDS + one barrier remain only for the per-ray count (after the stores).
// No device-scope atomics / NT hints (r4: agent atomics nuke per-XCD L2).
// ---------------------------------------------------------------------------
__global__ __launch_bounds__(512)
void sample_kernel(const float* __restrict__ rays_o, const float* __restrict__ rays_d,
                   const float* __restrict__ aabb,
                   const unsigned int* __restrict__ bits,
                   float* __restrict__ out, int* __restrict__ counts)
{
    const int r = blockIdx.x;
    const int s = threadIdx.x;
    const int wir = s >> 6;          // wave-in-ray 0..7
    const int lane = s & 63;

    const float ox = rays_o[3 * r + 0], oy = rays_o[3 * r + 1], oz = rays_o[3 * r + 2];
    const float dx = rays_d[3 * r + 0], dy = rays_d[3 * r + 1], dz = rays_d[3 * r + 2];
    const float a0x = aabb[0], a0y = aabb[1], a0z = aabb[2];
    const float a1x = aabb[3], a1y = aabb[4], a1z = aabb[5];

    const float sdx = (fabsf(dx) > 1e-10f) ? dx : 1e-10f;
    const float sdy = (fabsf(dy) > 1e-10f) ? dy : 1e-10f;
    const float sdz = (fabsf(dz) > 1e-10f) ? dz : 1e-10f;
    const float invx = __fdiv_rn(1.0f, sdx);
    const float invy = __fdiv_rn(1.0f, sdy);
    const float invz = __fdiv_rn(1.0f, sdz);

    const float t0x = __fmul_rn(__fsub_rn(a0x, ox), invx);
    const float t1x = __fmul_rn(__fsub_rn(a1x, ox), invx);
    const float t0y = __fmul_rn(__fsub_rn(a0y, oy), invy);
    const float t1y = __fmul_rn(__fsub_rn(a1y, oy), invy);
    const float t0z = __fmul_rn(__fsub_rn(a0z, oz), invz);
    const float t1z = __fmul_rn(__fsub_rn(a1z, oz), invz);

    const float tmin = fmaxf(fmaxf(fmaxf(fminf(t0x, t1x), fminf(t0y, t1y)), fminf(t0z, t1z)), 0.05f);
    const float tmax = fminf(fminf(fminf(fmaxf(t0x, t1x), fmaxf(t0y, t1y)), fmaxf(t0z, t1z)), 3.0f);

    const float step_f = (float)((3.0 - 0.05) / 512.0);
    const float start = __fadd_rn(0.05f, __fmul_rn((float)s, step_f));
    const float end   = __fadd_rn(0.05f, __fmul_rn((float)(s + 1), step_f));
    const float mid   = __fmul_rn(0.5f, __fadd_rn(start, end));

    const float px = __fadd_rn(ox, __fmul_rn(dx, mid));
    const float py = __fadd_rn(oy, __fmul_rn(dy, mid));
    const float pz = __fadd_rn(oz, __fmul_rn(dz, mid));

    const float scx = __fdiv_rn(__fsub_rn(px, a0x), __fsub_rn(a1x, a0x));
    const float scy = __fdiv_rn(__fsub_rn(py, a0y), __fsub_rn(a1y, a0y));
    const float scz = __fdiv_rn(__fsub_rn(pz, a0z), __fsub_rn(a1z, a0z));

    const bool inside = (scx >= 0.0f) && (scx < 1.0f) &&
                        (scy >= 0.0f) && (scy < 1.0f) &&
                        (scz >= 0.0f) && (scz < 1.0f);
    const bool geom = inside && (start >= tmin) && (end <= tmax);

    bool valid = false;
    if (geom) {
        int gx = (int)__fmul_rn(scx, (float)GRID_R);
        int gy = (int)__fmul_rn(scy, (float)GRID_R);
        int gz = (int)__fmul_rn(scz, (float)GRID_R);
        gx = min(max(gx, 0), GRID_R - 1);
        gy = min(max(gy, 0), GRID_R - 1);
        gz = min(max(gz, 0), GRID_R - 1);
        const int lin = (gx * GRID_R + gy) * GRID_R + gz;
        valid = (bits[lin >> 5] >> (lin & 31)) & 1u;
    }

    // wave's full 64-sample validity mask, in-register, uniform across lanes
    const unsigned long long b = __ballot(valid);

    // region base pointers (float4 units)
    vfloat4* const f4 = (vfloat4*)out;
    const long o_f4  = (long)r * 384 + wir * 48;                      // origins
    const long d_f4  = (3L * NS) / 4 + (long)r * 384 + wir * 48;      // dirs
    const long sf_f4 = (6L * NS) / 4 + (long)r * 128 + wir * 16;      // s_flat
    const long ef_f4 = (7L * NS) / 4 + (long)r * 128 + wir * 16;      // e_flat
    const long ri_f4 = (8L * NS + 2L * N_RAYS) / 4 + (long)r * 128 + wir * 16;
    const long mk_f4 = ri_f4 + NS / 4;

    const int step0 = wir * 64;     // ray-local step index of this wave's window

    // helper lambdas (byte-identical _rn expressions)
    auto od_vec = [&](int k, bool dir) {
        vfloat4 v;
#pragma unroll
        for (int j = 0; j < 4; ++j) {
            const int ff = 4 * k + j;        // float index in wave's 192-float window
            const int smp = ff / 3;          // local sample 0..63
            const int c = ff - smp * 3;
            const bool m = (b >> smp) & 1ull;
            const float oc = (c == 0) ? ox : ((c == 1) ? oy : oz);
            const float dc = (c == 0) ? dx : ((c == 1) ? dy : dz);
            v[j] = m ? (dir ? dc : oc) : 0.0f;
        }
        return v;
    };
    auto se_vec = [&](int k, int plus) {
        vfloat4 v;
#pragma unroll
        for (int j = 0; j < 4; ++j) {
            const int smp = 4 * k + j;       // local sample
            const bool m = (b >> smp) & 1ull;
            v[j] = m ? __fadd_rn(0.05f, __fmul_rn((float)(step0 + smp + plus), step_f)) : 0.0f;
        }
        return v;
    };

    // pass 1: lanes 0-47 -> origins, lanes 48-63 -> s_flat
    if (lane < 48) {
        f4[o_f4 + lane] = od_vec(lane, false);
    } else {
        f4[sf_f4 + (lane - 48)] = se_vec(lane - 48, 0);
    }
    // pass 2: lanes 0-47 -> dirs, lanes 48-63 -> e_flat
    if (lane < 48) {
        f4[d_f4 + lane] = od_vec(lane, true);
    } else {
        f4[ef_f4 + (lane - 48)] = se_vec(lane - 48, 1);
    }
    // pass 3: lanes 0-15 -> ray_indices, lanes 16-31 -> mask
    if (lane < 16) {
        vfloat4 v = {(float)r, (float)r, (float)r, (float)r};
        f4[ri_f4 + lane] = v;
    } else if (lane < 32) {
        const int k = lane - 16;
        vfloat4 v;
#pragma unroll
        for (int j = 0; j < 4; ++j) {
            const int smp = 4 * k + j;
            v[j] = ((b >> smp) & 1ull) ? 1.0f : 0.0f;
        }
        f4[mk_f4 + k] = v;
    }

    // per-ray count (after the stores; one barrier, 8 LDS words)
    __shared__ int wcnt[8];
    if (lane == 0) wcnt[wir] = __popcll(b);
    __syncthreads();
    if (s == 0) {
        int t = 0;
#pragma unroll
        for (int w = 0; w < 8; ++w) t += wcnt[w];
        counts[r] = t;
    }
}

// ---------------------------------------------------------------------------
// scan_kernel: exclusive scan of 16384 counts -> packed_info as floats.
// Shfl wave-scan (2 barriers instead of 20), vectorized loads and stores.
// ---------------------------------------------------------------------------
__global__ __launch_bounds__(1024)
void scan_kernel(const int* __restrict__ counts, float* __restrict__ packed)
{
    const int tid = threadIdx.x;
    const int lane = tid & 63;
    const int w = tid >> 6;            // wave 0..15
    const int base = tid * 16;

    int c[16];
#pragma unroll
    for (int i = 0; i < 16; i += 4) {
        const int4 q = ((const int4*)counts)[(base + i) >> 2];
        c[i + 0] = q.x; c[i + 1] = q.y; c[i + 2] = q.z; c[i + 3] = q.w;
    }
    int ts = 0;
#pragma unroll
    for (int i = 0; i < 16; ++i) ts += c[i];

    // inclusive wave scan of thread sums
    int incl = ts;
#pragma unroll
    for (int off = 1; off < 64; off <<= 1) {
        const int n = __shfl_up(incl, off);
        if (lane >= off) incl += n;
    }

    __shared__ int wtot[16];
    if (lane == 63) wtot[w] = incl;
    __syncthreads();

    int wbase = 0;
#pragma unroll
    for (int i = 0; i < 16; ++i) wbase += (i < w) ? wtot[i] : 0;

    int run = wbase + (incl - ts);     // exclusive prefix for this thread's chunk
#pragma unroll
    for (int i = 0; i < 16; ++i) {
        vfloat2 v = {(float)run, (float)c[i]};
        ((vfloat2*)packed)[base + i] = v;
        run += c[i];
    }
}

// ===========================================================================
// Fallback path (only if ws is too small for the bit grid).
// ===========================================================================
__global__ void detect_dtype(const void* __restrict__ occ, int* __restrict__ flag) {
    __shared__ int ok_int, ok_flt;
    if (threadIdx.x == 0) { ok_int = 1; ok_flt = 1; }
    __syncthreads();
    const int*   pi = (const int*)occ;
    const float* pf = (const float*)occ;
    for (int i = threadIdx.x; i < 1024; i += blockDim.x) {
        int v = pi[i];
        if (v != 0 && v != 1) atomicAnd(&ok_int, 0);
        float f = pf[i];
        if (!(f == 0.0f || f == 1.0f)) atomicAnd(&ok_flt, 0);
    }
    __syncthreads();
    if (threadIdx.x == 0) flag[0] = ok_int ? 0 : (ok_flt ? 1 : 2);
}

__global__ __launch_bounds__(512)
void sample_fallback(const float* __restrict__ rays_o, const float* __restrict__ rays_d,
                     const float* __restrict__ aabb, const void* __restrict__ occ,
                     const int* __restrict__ flag_p, float* __restrict__ out,
                     int* __restrict__ counts)
{
    const int r = blockIdx.x;
    const int s = threadIdx.x;
    const int mode = flag_p[0];
    const float ox = rays_o[3 * r + 0], oy = rays_o[3 * r + 1], oz = rays_o[3 * r + 2];
    const float dx = rays_d[3 * r + 0], dy = rays_d[3 * r + 1], dz = rays_d[3 * r + 2];
    const float a0x = aabb[0], a0y = aabb[1], a0z = aabb[2];
    const float a1x = aabb[3], a1y = aabb[4], a1z = aabb[5];
    const float sdx = (fabsf(dx) > 1e-10f) ? dx : 1e-10f;
    const float sdy = (fabsf(dy) > 1e-10f) ? dy : 1e-10f;
    const float sdz = (fabsf(dz) > 1e-10f) ? dz : 1e-10f;
    const float invx = __fdiv_rn(1.0f, sdx);
    const float invy = __fdiv_rn(1.0f, sdy);
    const float invz = __fdiv_rn(1.0f, sdz);
    const float t0x = __fmul_rn(__fsub_rn(a0x, ox), invx);
    const float t1x = __fmul_rn(__fsub_rn(a1x, ox), invx);
    const float t0y = __fmul_rn(__fsub_rn(a0y, oy), invy);
    const float t1y = __fmul_rn(__fsub_rn(a1y, oy), invy);
    const float t0z = __fmul_rn(__fsub_rn(a0z, oz), invz);
    const float t1z = __fmul_rn(__fsub_rn(a1z, oz), invz);
    const float tmin = fmaxf(fmaxf(fmaxf(fminf(t0x, t1x), fminf(t0y, t1y)), fminf(t0z, t1z)), 0.05f);
    const float tmax = fminf(fminf(fminf(fmaxf(t0x, t1x), fmaxf(t0y, t1y)), fmaxf(t0z, t1z)), 3.0f);
    const float step_f = (float)((3.0 - 0.05) / 512.0);
    const float start = __fadd_rn(0.05f, __fmul_rn((float)s, step_f));
    const float end   = __fadd_rn(0.05f, __fmul_rn((float)(s + 1), step_f));
    const float mid   = __fmul_rn(0.5f, __fadd_rn(start, end));
    const float px = __fadd_rn(ox, __fmul_rn(dx, mid));
    const float py = __fadd_rn(oy, __fmul_rn(dy, mid));
    const float pz = __fadd_rn(oz, __fmul_rn(dz, mid));
    const float scx = __fdiv_rn(__fsub_rn(px, a0x), __fsub_rn(a1x, a0x));
    const float scy = __fdiv_rn(__fsub_rn(py, a0y), __fsub_rn(a1y, a0y));
    const float scz = __fdiv_rn(__fsub_rn(pz, a0z), __fsub_rn(a1z, a0z));
    const bool inside = (scx >= 0.0f) && (scx < 1.0f) &&
                        (scy >= 0.0f) && (scy < 1.0f) &&
                        (scz >= 0.0f) && (scz < 1.0f);
    const bool geom = inside && (start >= tmin) && (end <= tmax);
    bool valid = false;
    if (geom) {
        int gx = (int)__fmul_rn(scx, (float)GRID_R);
        int gy = (int)__fmul_rn(scy, (float)GRID_R);
        int gz = (int)__fmul_rn(scz, (float)GRID_R);
        gx = min(max(gx, 0), GRID_R - 1);
        gy = min(max(gy, 0), GRID_R - 1);
        gz = min(max(gz, 0), GRID_R - 1);
        const int lin = (gx * GRID_R + gy) * GRID_R + gz;
        if (mode == 0)      valid = ((const int*)occ)[lin] != 0;
        else if (mode == 1) valid = ((const float*)occ)[lin] != 0.0f;
        else                valid = ((const unsigned char*)occ)[lin] != 0;
    }
    const int i = (r << 9) | s;
    float* og = out;
    float* dr = out + 3L * NS;
    float* sf = out + 6L * NS;
    float* ef = out + 7L * NS;
    float* ri = out + 8L * NS + 2L * N_RAYS;
    float* mk = ri + (long)NS;
    og[3 * i + 0] = valid ? ox : 0.0f;
    og[3 * i + 1] = valid ? oy : 0.0f;
    og[3 * i + 2] = valid ? oz : 0.0f;
    dr[3 * i + 0] = valid ? dx : 0.0f;
    dr[3 * i + 1] = valid ? dy : 0.0f;
    dr[3 * i + 2] = valid ? dz : 0.0f;
    sf[i] = valid ? start : 0.0f;
    ef[i] = valid ? end : 0.0f;
    ri[i] = (float)r;
    mk[i] = valid ? 1.0f : 0.0f;
    const unsigned long long b = __ballot(valid);
    __shared__ int wcount[8];
    if ((threadIdx.x & 63) == 0) wcount[threadIdx.x >> 6] = __popcll(b);
    __syncthreads();
    if (threadIdx.x == 0) {
        int t = 0;
#pragma unroll
        for (int w = 0; w < 8; ++w) t += wcount[w];
        counts[r] = t;
    }
}

extern "C" void kernel_launch(void* const* d_in, const int* in_sizes, int n_in,
                              void* d_out, int out_size, void* d_ws, size_t ws_size,
                              hipStream_t stream) {
    const float* rays_o = (const float*)d_in[0];
    const float* rays_d = (const float*)d_in[1];
    const float* aabb   = (const float*)d_in[2];
    const void*  occ    = d_in[3];
    float* out = (float*)d_out;

    int* counts = (int*)((char*)d_ws + WS_COUNTS_OFF);

    if (ws_size >= (size_t)WS_NEEDED) {
        unsigned long long* bits64 = (unsigned long long*)((char*)d_ws + WS_BITS_OFF);
        pack_occ<<<N_CELLS / 256, 256, 0, stream>>>(occ, bits64);
        sample_kernel<<<N_RAYS, 512, 0, stream>>>(rays_o, rays_d, aabb,
                                                  (const unsigned int*)bits64,
                                                  out, counts);
    } else {
        int* flag = (int*)d_ws;
        detect_dtype<<<1, 256, 0, stream>>>(occ, flag);
        sample_fallback<<<N_RAYS, 512, 0, stream>>>(rays_o, rays_d, aabb, occ, flag, out, counts);
    }
    scan_kernel<<<1, 1024, 0, stream>>>(counts, out + 8L * NS);
}

// Round 7
// 360.974 us; speedup vs baseline: 1.1248x; 1.1248x over previous
//
#include <hip/hip_runtime.h>

#define N_RAYS 16384
#define MAX_STEPS 512
#define GRID_R 128
#define N_CELLS (GRID_R * GRID_R * GRID_R) /* 2097152 */
#define NS (N_RAYS * MAX_STEPS)            /* 8388608 samples */

typedef float vfloat4 __attribute__((ext_vector_type(4)));
typedef float vfloat2 __attribute__((ext_vector_type(2)));

// ws layout (bytes):
//   [0)       flag (fallback only)
//   [1024)    counts (16384 ints)
//   [131072)  bit grid (N_CELLS/8 = 262144 B)
#define WS_COUNTS_OFF 1024
#define WS_BITS_OFF 131072
#define WS_NEEDED (WS_BITS_OFF + N_CELLS / 8)

// ---------------------------------------------------------------------------
// pack_occ: self-detects occ dtype from the global first 1024 words (uniform
// across all blocks), then compresses its 256-cell slice to 1 bit/cell.
// mode 0 = int32 (0/1), mode 1 = float32 (0.0/1.0), mode 2 = uint8.
// ---------------------------------------------------------------------------
__global__ __launch_bounds__(256)
void pack_occ(const void* __restrict__ occ, unsigned long long* __restrict__ bits) {
    const int* pi = (const int*)occ;
    const float* pf = (const float*)occ;
    bool oki = true, okf = true;
#pragma unroll
    for (int k = 0; k < 4; ++k) {
        const int w = threadIdx.x * 4 + k;
        const int v = pi[w];
        oki = oki && (v == 0 || v == 1);
        const float f = pf[w];
        okf = okf && (f == 0.0f || f == 1.0f);
    }
    oki = __all(oki); okf = __all(okf);
    __shared__ int s_oki[4], s_okf[4];
    if ((threadIdx.x & 63) == 0) { s_oki[threadIdx.x >> 6] = oki; s_okf[threadIdx.x >> 6] = okf; }
    __syncthreads();
    const bool all_i = s_oki[0] && s_oki[1] && s_oki[2] && s_oki[3];
    const bool all_f = s_okf[0] && s_okf[1] && s_okf[2] && s_okf[3];
    const int mode = all_i ? 0 : (all_f ? 1 : 2);

    const int idx = blockIdx.x * 256 + threadIdx.x;
    bool v;
    if (mode == 0)      v = pi[idx] != 0;
    else if (mode == 1) v = pf[idx] != 0.0f;
    else                v = ((const unsigned char*)occ)[idx] != 0;
    const unsigned long long b = __ballot(v);
    if ((threadIdx.x & 63) == 0) bits[idx >> 6] = b;
}

// ---------------------------------------------------------------------------
// sample_kernel: one block per ray, one thread per step (r2 structure — the
// measured best: float lmask in LDS, one barrier, full-wave 1 KB coalesced
// float4 stores per region). _rn arithmetic (numpy ref = no FMA contraction).
// No device-scope atomics / NT hints (r4: agent atomics nuke per-XCD L2;
// r6: sub-wave store windows regress vs full-wave stores).
// ---------------------------------------------------------------------------
__global__ __launch_bounds__(512)
void sample_kernel(const float* __restrict__ rays_o, const float* __restrict__ rays_d,
                   const float* __restrict__ aabb,
                   const unsigned int* __restrict__ bits,
                   float* __restrict__ out, int* __restrict__ counts)
{
    const int r = blockIdx.x;
    const int s = threadIdx.x;

    const float ox = rays_o[3 * r + 0], oy = rays_o[3 * r + 1], oz = rays_o[3 * r + 2];
    const float dx = rays_d[3 * r + 0], dy = rays_d[3 * r + 1], dz = rays_d[3 * r + 2];
    const float a0x = aabb[0], a0y = aabb[1], a0z = aabb[2];
    const float a1x = aabb[3], a1y = aabb[4], a1z = aabb[5];

    const float sdx = (fabsf(dx) > 1e-10f) ? dx : 1e-10f;
    const float sdy = (fabsf(dy) > 1e-10f) ? dy : 1e-10f;
    const float sdz = (fabsf(dz) > 1e-10f) ? dz : 1e-10f;
    const float invx = __fdiv_rn(1.0f, sdx);
    const float invy = __fdiv_rn(1.0f, sdy);
    const float invz = __fdiv_rn(1.0f, sdz);

    const float t0x = __fmul_rn(__fsub_rn(a0x, ox), invx);
    const float t1x = __fmul_rn(__fsub_rn(a1x, ox), invx);
    const float t0y = __fmul_rn(__fsub_rn(a0y, oy), invy);
    const float t1y = __fmul_rn(__fsub_rn(a1y, oy), invy);
    const float t0z = __fmul_rn(__fsub_rn(a0z, oz), invz);
    const float t1z = __fmul_rn(__fsub_rn(a1z, oz), invz);

    const float tmin = fmaxf(fmaxf(fmaxf(fminf(t0x, t1x), fminf(t0y, t1y)), fminf(t0z, t1z)), 0.05f);
    const float tmax = fminf(fminf(fminf(fmaxf(t0x, t1x), fmaxf(t0y, t1y)), fmaxf(t0z, t1z)), 3.0f);

    const float step_f = (float)((3.0 - 0.05) / 512.0);
    const float start = __fadd_rn(0.05f, __fmul_rn((float)s, step_f));
    const float end   = __fadd_rn(0.05f, __fmul_rn((float)(s + 1), step_f));
    const float mid   = __fmul_rn(0.5f, __fadd_rn(start, end));

    const float px = __fadd_rn(ox, __fmul_rn(dx, mid));
    const float py = __fadd_rn(oy, __fmul_rn(dy, mid));
    const float pz = __fadd_rn(oz, __fmul_rn(dz, mid));

    const float scx = __fdiv_rn(__fsub_rn(px, a0x), __fsub_rn(a1x, a0x));
    const float scy = __fdiv_rn(__fsub_rn(py, a0y), __fsub_rn(a1y, a0y));
    const float scz = __fdiv_rn(__fsub_rn(pz, a0z), __fsub_rn(a1z, a0z));

    const bool inside = (scx >= 0.0f) && (scx < 1.0f) &&
                        (scy >= 0.0f) && (scy < 1.0f) &&
                        (scz >= 0.0f) && (scz < 1.0f);
    const bool geom = inside && (start >= tmin) && (end <= tmax);

    bool valid = false;
    if (geom) {
        int gx = (int)__fmul_rn(scx, (float)GRID_R);
        int gy = (int)__fmul_rn(scy, (float)GRID_R);
        int gz = (int)__fmul_rn(scz, (float)GRID_R);
        gx = min(max(gx, 0), GRID_R - 1);
        gy = min(max(gy, 0), GRID_R - 1);
        gz = min(max(gz, 0), GRID_R - 1);
        const int lin = (gx * GRID_R + gy) * GRID_R + gz;
        valid = (bits[lin >> 5] >> (lin & 31)) & 1u;
    }

    // ---- validity to LDS (float, broadcast-friendly), count via ballot ----
    __shared__ float lmask[512];
    __shared__ int wcount[8];
    lmask[s] = valid ? 1.0f : 0.0f;
    const unsigned long long b = __ballot(valid);
    if ((s & 63) == 0) wcount[s >> 6] = __popcll(b);
    __syncthreads();

    // ---- origins & dirs: 384 float4 each per block (interleaved xyz) ----
    if (s < 384) {
        const int f = 4 * s;
        vfloat4 vo, vd;
#pragma unroll
        for (int k = 0; k < 4; ++k) {
            const int ff = f + k;
            const int smp = ff / 3;
            const int c = ff - smp * 3;
            const float m = lmask[smp];
            const float oc = (c == 0) ? ox : ((c == 1) ? oy : oz);
            const float dc = (c == 0) ? dx : ((c == 1) ? dy : dz);
            vo[k] = __fmul_rn(m, oc);
            vd[k] = __fmul_rn(m, dc);
        }
        ((vfloat4*)out)[(long)r * 384 + s] = vo;
        ((vfloat4*)(out + 3L * NS))[(long)r * 384 + s] = vd;
    }

    // ---- s_flat / e_flat / ray_indices / mask: one float4 per thread ----
    {
        const int grp = s >> 7;    // wave-uniform (boundaries at multiples of 64)
        const int t = s & 127;
        vfloat4 v;
#pragma unroll
        for (int k = 0; k < 4; ++k) {
            const int smp = 4 * t + k;
            const float m = lmask[smp];
            float val;
            if (grp == 0)      val = __fmul_rn(m, __fadd_rn(0.05f, __fmul_rn((float)smp, step_f)));
            else if (grp == 1) val = __fmul_rn(m, __fadd_rn(0.05f, __fmul_rn((float)(smp + 1), step_f)));
            else if (grp == 2) val = (float)r;
            else               val = m;
            v[k] = val;
        }
        float* basep;
        if (grp == 0)      basep = out + 6L * NS;
        else if (grp == 1) basep = out + 7L * NS;
        else if (grp == 2) basep = out + 8L * NS + 2L * N_RAYS;
        else               basep = out + 8L * NS + 2L * N_RAYS + (long)NS;
        ((vfloat4*)basep)[(long)r * 128 + t] = v;
    }

    if (s == 0) {
        int tot = 0;
#pragma unroll
        for (int w = 0; w < 8; ++w) tot += wcount[w];
        counts[r] = tot;
    }
}

// ---------------------------------------------------------------------------
// scan_kernel: exclusive scan of 16384 counts -> packed_info as floats.
// Shfl wave-scan (2 barriers), vectorized loads and stores.
// ---------------------------------------------------------------------------
__global__ __launch_bounds__(1024)
void scan_kernel(const int* __restrict__ counts, float* __restrict__ packed)
{
    const int tid = threadIdx.x;
    const int lane = tid & 63;
    const int w = tid >> 6;            // wave 0..15
    const int base = tid * 16;

    int c[16];
#pragma unroll
    for (int i = 0; i < 16; i += 4) {
        const int4 q = ((const int4*)counts)[(base + i) >> 2];
        c[i + 0] = q.x; c[i + 1] = q.y; c[i + 2] = q.z; c[i + 3] = q.w;
    }
    int ts = 0;
#pragma unroll
    for (int i = 0; i < 16; ++i) ts += c[i];

    int incl = ts;
#pragma unroll
    for (int off = 1; off < 64; off <<= 1) {
        const int n = __shfl_up(incl, off);
        if (lane >= off) incl += n;
    }

    __shared__ int wtot[16];
    if (lane == 63) wtot[w] = incl;
    __syncthreads();

    int wbase = 0;
#pragma unroll
    for (int i = 0; i < 16; ++i) wbase += (i < w) ? wtot[i] : 0;

    int run = wbase + (incl - ts);
#pragma unroll
    for (int i = 0; i < 16; ++i) {
        vfloat2 v = {(float)run, (float)c[i]};
        ((vfloat2*)packed)[base + i] = v;
        run += c[i];
    }
}

// ===========================================================================
// Fallback path (only if ws is too small for the bit grid).
// ===========================================================================
__global__ void detect_dtype(const void* __restrict__ occ, int* __restrict__ flag) {
    __shared__ int ok_int, ok_flt;
    if (threadIdx.x == 0) { ok_int = 1; ok_flt = 1; }
    __syncthreads();
    const int*   pi = (const int*)occ;
    const float* pf = (const float*)occ;
    for (int i = threadIdx.x; i < 1024; i += blockDim.x) {
        int v = pi[i];
        if (v != 0 && v != 1) atomicAnd(&ok_int, 0);
        float f = pf[i];
        if (!(f == 0.0f || f == 1.0f)) atomicAnd(&ok_flt, 0);
    }
    __syncthreads();
    if (threadIdx.x == 0) flag[0] = ok_int ? 0 : (ok_flt ? 1 : 2);
}

__global__ __launch_bounds__(512)
void sample_fallback(const float* __restrict__ rays_o, const float* __restrict__ rays_d,
                     const float* __restrict__ aabb, const void* __restrict__ occ,
                     const int* __restrict__ flag_p, float* __restrict__ out,
                     int* __restrict__ counts)
{
    const int r = blockIdx.x;
    const int s = threadIdx.x;
    const int mode = flag_p[0];
    const float ox = rays_o[3 * r + 0], oy = rays_o[3 * r + 1], oz = rays_o[3 * r + 2];
    const float dx = rays_d[3 * r + 0], dy = rays_d[3 * r + 1], dz = rays_d[3 * r + 2];
    const float a0x = aabb[0], a0y = aabb[1], a0z = aabb[2];
    const float a1x = aabb[3], a1y = aabb[4], a1z = aabb[5];
    const float sdx = (fabsf(dx) > 1e-10f) ? dx : 1e-10f;
    const float sdy = (fabsf(dy) > 1e-10f) ? dy : 1e-10f;
    const float sdz = (fabsf(dz) > 1e-10f) ? dz : 1e-10f;
    const float invx = __fdiv_rn(1.0f, sdx);
    const float invy = __fdiv_rn(1.0f, sdy);
    const float invz = __fdiv_rn(1.0f, sdz);
    const float t0x = __fmul_rn(__fsub_rn(a0x, ox), invx);
    const float t1x = __fmul_rn(__fsub_rn(a1x, ox), invx);
    const float t0y = __fmul_rn(__fsub_rn(a0y, oy), invy);
    const float t1y = __fmul_rn(__fsub_rn(a1y, oy), invy);
    const float t0z = __fmul_rn(__fsub_rn(a0z, oz), invz);
    const float t1z = __fmul_rn(__fsub_rn(a1z, oz), invz);
    const float tmin = fmaxf(fmaxf(fmaxf(fminf(t0x, t1x), fminf(t0y, t1y)), fminf(t0z, t1z)), 0.05f);
    const float tmax = fminf(fminf(fminf(fmaxf(t0x, t1x), fmaxf(t0y, t1y)), fmaxf(t0z, t1z)), 3.0f);
    const float step_f = (float)((3.0 - 0.05) / 512.0);
    const float start = __fadd_rn(0.05f, __fmul_rn((float)s, step_f));
    const float end   = __fadd_rn(0.05f, __fmul_rn((float)(s + 1), step_f));
    const float mid   = __fmul_rn(0.5f, __fadd_rn(start, end));
    const float px = __fadd_rn(ox, __fmul_rn(dx, mid));
    const float py = __fadd_rn(oy, __fmul_rn(dy, mid));
    const float pz = __fadd_rn(oz, __fmul_rn(dz, mid));
    const float scx = __fdiv_rn(__fsub_rn(px, a0x), __fsub_rn(a1x, a0x));
    const float scy = __fdiv_rn(__fsub_rn(py, a0y), __fsub_rn(a1y, a0y));
    const float scz = __fdiv_rn(__fsub_rn(pz, a0z), __fsub_rn(a1z, a0z));
    const bool inside = (scx >= 0.0f) && (scx < 1.0f) &&
                        (scy >= 0.0f) && (scy < 1.0f) &&
                        (scz >= 0.0f) && (scz < 1.0f);
    const bool geom = inside && (start >= tmin) && (end <= tmax);
    bool valid = false;
    if (geom) {
        int gx = (int)__fmul_rn(scx, (float)GRID_R);
        int gy = (int)__fmul_rn(scy, (float)GRID_R);
        int gz = (int)__fmul_rn(scz, (float)GRID_R);
        gx = min(max(gx, 0), GRID_R - 1);
        gy = min(max(gy, 0), GRID_R - 1);
        gz = min(max(gz, 0), GRID_R - 1);
        const int lin = (gx * GRID_R + gy) * GRID_R + gz;
        if (mode == 0)      valid = ((const int*)occ)[lin] != 0;
        else if (mode == 1) valid = ((const float*)occ)[lin] != 0.0f;
        else                valid = ((const unsigned char*)occ)[lin] != 0;
    }
    const int i = (r << 9) | s;
    float* og = out;
    float* dr = out + 3L * NS;
    float* sf = out + 6L * NS;
    float* ef = out + 7L * NS;
    float* ri = out + 8L * NS + 2L * N_RAYS;
    float* mk = ri + (long)NS;
    og[3 * i + 0] = valid ? ox : 0.0f;
    og[3 * i + 1] = valid ? oy : 0.0f;
    og[3 * i + 2] = valid ? oz : 0.0f;
    dr[3 * i + 0] = valid ? dx : 0.0f;
    dr[3 * i + 1] = valid ? dy : 0.0f;
    dr[3 * i + 2] = valid ? dz : 0.0f;
    sf[i] = valid ? start : 0.0f;
    ef[i] = valid ? end : 0.0f;
    ri[i] = (float)r;
    mk[i] = valid ? 1.0f : 0.0f;
    const unsigned long long b = __ballot(valid);
    __shared__ int wcount[8];
    if ((threadIdx.x & 63) == 0) wcount[threadIdx.x >> 6] = __popcll(b);
    __syncthreads();
    if (threadIdx.x == 0) {
        int t = 0;
#pragma unroll
        for (int w = 0; w < 8; ++w) t += wcount[w];
        counts[r] = t;
    }
}

extern "C" void kernel_launch(void* const* d_in, const int* in_sizes, int n_in,
                              void* d_out, int out_size, void* d_ws, size_t ws_size,
                              hipStream_t stream) {
    const float* rays_o = (const float*)d_in[0];
    const float* rays_d = (const float*)d_in[1];
    const float* aabb   = (const float*)d_in[2];
    const void*  occ    = d_in[3];
    float* out = (float*)d_out;

    int* counts = (int*)((char*)d_ws + WS_COUNTS_OFF);

    if (ws_size >= (size_t)WS_NEEDED) {
        unsigned long long* bits64 = (unsigned long long*)((char*)d_ws + WS_BITS_OFF);
        pack_occ<<<N_CELLS / 256, 256, 0, stream>>>(occ, bits64);
        sample_kernel<<<N_RAYS, 512, 0, stream>>>(rays_o, rays_d, aabb,
                                                  (const unsigned int*)bits64,
                                                  out, counts);
    } else {
        int* flag = (int*)d_ws;
        detect_dtype<<<1, 256, 0, stream>>>(occ, flag);
        sample_fallback<<<N_RAYS, 512, 0, stream>>>(rays_o, rays_d, aabb, occ, flag, out, counts);
    }
    scan_kernel<<<1, 1024, 0, stream>>>(counts, out + 8L * NS);
}